// Round 3
// baseline (434.550 us; speedup 1.0000x reference)
//
#include <hip/hip_runtime.h>
#include <hip/hip_bf16.h>

// ReadoutLayer: Wx = x @ W^T (+b cancels under BN), BatchNorm(train) over B*T,
// then ut = a*ut + (1-a)*wxn per t with acc += softmax(ut, axis=H).
// R3: fix R2's register-spill (launch_bounds 512,2 — R2's (512,4) capped the
// unified VGPR/AGPR file at 128 and spilled staging regs to scratch: 230 MB of
// phantom WRITE_SIZE). Tail: register shfl-reduce softmax (no 40KB tile),
// batched-prefetch chunk scan, vectorized chunk_agg.

namespace {
constexpr int kB = 32;
constexpr int kT = 2000;
constexpr int kD = 512;
constexpr int kH = 512;
constexpr int kM = kB * kT;   // 64000 rows
constexpr int kL = 20;        // chunk length
constexpr int kC = kT / kL;   // 100 chunks per batch
constexpr float kALo = 0.81873075307798182f;  // exp(-1/5)
constexpr float kAHi = 0.96078943915232320f;  // exp(-1/25)
constexpr int kPad = 40;      // LDS row stride (els); 16B-aligned rows

typedef __bf16 bf16x8 __attribute__((ext_vector_type(8)));
typedef float floatx16 __attribute__((ext_vector_type(16)));

__device__ __forceinline__ float bf2f(unsigned short u) {
  return __builtin_bit_cast(float, (unsigned)u << 16);
}

// ---------- K0: W f32 -> bf16 (once; L2-resident for the GEMM) ----------
__global__ __launch_bounds__(256) void wcvt_k(const float* __restrict__ W,
                                              __bf16* __restrict__ Wbf) {
  const int t = blockIdx.x * 256 + threadIdx.x;  // 128 blocks x 256 thr x 8 els
  const float4 a0 = ((const float4*)W)[t * 2];
  const float4 a1 = ((const float4*)W)[t * 2 + 1];
  bf16x8 v;
  v[0] = (__bf16)a0.x; v[1] = (__bf16)a0.y; v[2] = (__bf16)a0.z; v[3] = (__bf16)a0.w;
  v[4] = (__bf16)a1.x; v[5] = (__bf16)a1.y; v[6] = (__bf16)a1.z; v[7] = (__bf16)a1.w;
  *(bf16x8*)(Wbf + (size_t)t * 8) = v;
}

// ---------- K1: GEMM 64 rows x full 512 cols per block + fused BN stats ----------
// 512 threads = 8 waves; wave w: row-tile rt=w>>2 (32 rows), col-tiles (w&3)*4..+4.
// launch_bounds(512,2): 256-reg budget — 64 AGPR acc + staging fits, NO spills.
__global__ __launch_bounds__(512, 2) void gemm_k(const float* __restrict__ X,
                                                 const __bf16* __restrict__ Wbf,
                                                 unsigned short* __restrict__ Wxb,
                                                 float* __restrict__ sums) {
  __shared__ __bf16 As[64][kPad];    // [m][k] 32-k slab
  __shared__ __bf16 Bs[512][kPad];   // [n][k] 32-k slab
  __shared__ float sred[2][kH];
  const int tid = threadIdx.x;
  const size_t row0 = (size_t)blockIdx.x * 64;
  const int w = tid >> 6, L = tid & 63;
  const int rt = w >> 2;             // 0/1
  const int ct0 = (w & 3) * 4;       // col-tile base
  const int lhalf = L >> 5, l32 = L & 31;
  const int arow = tid >> 2, akq = tid & 3;  // A staging: threads 0..255
  const int bn0 = tid >> 2, bkq = tid & 3;   // B staging: 4 passes of 128 rows

  floatx16 acc[4] = {};
  float a_r[8];
  uint4 b_r[4];

  auto load_slab = [&](int kk) {
    if (tid < 256) {
      const float4* pa = (const float4*)(X + (row0 + arow) * kD + kk + akq * 8);
      const float4 x0 = pa[0], x1 = pa[1];
      a_r[0] = x0.x; a_r[1] = x0.y; a_r[2] = x0.z; a_r[3] = x0.w;
      a_r[4] = x1.x; a_r[5] = x1.y; a_r[6] = x1.z; a_r[7] = x1.w;
    }
#pragma unroll
    for (int j = 0; j < 4; ++j) {
      const int n = j * 128 + bn0;
      b_r[j] = *(const uint4*)(Wbf + (size_t)n * kD + kk + bkq * 8);
    }
  };
  auto store_slab = [&]() {
    if (tid < 256) {
      bf16x8 v;
#pragma unroll
      for (int j = 0; j < 8; ++j) v[j] = (__bf16)a_r[j];
      *(bf16x8*)&As[arow][akq * 8] = v;
    }
#pragma unroll
    for (int j = 0; j < 4; ++j)
      *(uint4*)&Bs[j * 128 + bn0][bkq * 8] = b_r[j];
  };

  load_slab(0);
#pragma unroll 1
  for (int s = 0; s < 16; ++s) {
    store_slab();
    __syncthreads();
    if (s < 15) load_slab((s + 1) * 32);  // prefetch overlaps MFMA phase
#pragma unroll
    for (int kh = 0; kh < 2; ++kh) {
      const bf16x8 af = *(const bf16x8*)&As[rt * 32 + l32][kh * 16 + lhalf * 8];
#pragma unroll
      for (int c = 0; c < 4; ++c) {
        const bf16x8 bfr = *(const bf16x8*)&Bs[(ct0 + c) * 32 + l32][kh * 16 + lhalf * 8];
        acc[c] = __builtin_amdgcn_mfma_f32_32x32x16_bf16(af, bfr, acc[c], 0, 0, 0);
      }
    }
    __syncthreads();
  }

  // ---- epilogue 1: column sums/sumsq for BN stats ----
  sred[0][tid] = 0.f;
  sred[1][tid] = 0.f;
  __syncthreads();
#pragma unroll
  for (int c = 0; c < 4; ++c) {
    float s = 0.f, q = 0.f;
#pragma unroll
    for (int r = 0; r < 16; ++r) {
      const float v = acc[c][r];
      s += v;
      q += v * v;
    }
    s += __shfl_xor(s, 32);
    q += __shfl_xor(q, 32);
    if (lhalf == 0) {
      atomicAdd(&sred[0][(ct0 + c) * 32 + l32], s);
      atomicAdd(&sred[1][(ct0 + c) * 32 + l32], q);
    }
  }
  // ---- epilogue 2: store Wx bf16, packed dword pairs via shfl ----
  // C/D layout (32x32): col = lane&31, row = 4*(lane>>5) + (reg&3) + 8*(reg>>2)
#pragma unroll
  for (int c = 0; c < 4; ++c) {
    const int col = (ct0 + c) * 32 + l32;
#pragma unroll
    for (int r = 0; r < 16; ++r) {
      const int row = rt * 32 + 4 * lhalf + (r & 3) + 8 * (r >> 2);
      const unsigned short u = __builtin_bit_cast(unsigned short, (__bf16)acc[c][r]);
      const unsigned un = __shfl_down((unsigned)u, 1);
      if ((l32 & 1) == 0)
        *(unsigned*)(Wxb + (row0 + row) * (size_t)kH + col) = (unsigned)u | (un << 16);
    }
  }
  __syncthreads();
  atomicAdd(&sums[tid], sred[0][tid]);
  atomicAdd(&sums[kH + tid], sred[1][tid]);
}

// ---------- K2: finalize BN scale/shift + alpha-derived params ----------
// prm: [0]=scale [512]=shift [1024]=a [1536]=1-a [2048]=a^L
__global__ __launch_bounds__(512) void finalize_k(const float* __restrict__ sums,
                                                  const float* __restrict__ alpha,
                                                  const float* __restrict__ gamma,
                                                  const float* __restrict__ beta,
                                                  float* __restrict__ prm) {
  const int h = threadIdx.x;
  const float inv_n = 1.0f / (float)kM;
  const float mean = sums[h] * inv_n;
  const float var = sums[kH + h] * inv_n - mean * mean;
  const float sc = gamma[h] * rsqrtf(var + 1e-5f);
  const float sh = beta[h] - mean * sc;
  const float a = fminf(fmaxf(alpha[h], kALo), kAHi);
  const float a2 = a * a, a4 = a2 * a2, a5 = a4 * a;
  const float a10 = a5 * a5, a20 = a10 * a10;
  prm[h] = sc;
  prm[kH + h] = sh;
  prm[2 * kH + h] = a;
  prm[3 * kH + h] = 1.0f - a;
  prm[4 * kH + h] = a20;
}

// ---------- K3: per-chunk aggregate v_c (2 h per thread, dword loads) ----------
__global__ __launch_bounds__(256) void chunk_agg_k(const unsigned short* __restrict__ Wxb,
                                                   const float* __restrict__ prm,
                                                   float* __restrict__ vbuf) {
  const int bc = blockIdx.x;
  const int b = bc / kC, c = bc % kC;
  const int tt = threadIdx.x;        // 0..255, h = 2*tt
  const float2 sc = ((const float2*)prm)[tt];
  const float2 sh = ((const float2*)(prm + kH))[tt];
  const float2 aa = ((const float2*)(prm + 2 * kH))[tt];
  const float2 om = ((const float2*)(prm + 3 * kH))[tt];
  const unsigned short* base = Wxb + ((size_t)b * kT + (size_t)c * kL) * kH + 2 * tt;
  float v0 = 0.f, v1 = 0.f;
#pragma unroll
  for (int i = 0; i < kL; ++i) {
    const unsigned p = *(const unsigned*)(base + (size_t)i * kH);
    const float w0 = bf2f((unsigned short)(p & 0xffff)) * sc.x + sh.x;
    const float w1 = bf2f((unsigned short)(p >> 16)) * sc.y + sh.y;
    v0 = aa.x * v0 + om.x * w0;
    v1 = aa.y * v1 + om.y * w1;
  }
  *(float2*)(vbuf + (size_t)bc * kH + 2 * tt) = make_float2(v0, v1);
}

// ---------- K4: chunk-boundary scan (vbuf -> ustart in place), batched prefetch ----------
__global__ __launch_bounds__(512) void chunk_scan_k(const float* __restrict__ ut0,
                                                    const float* __restrict__ prm,
                                                    float* __restrict__ vbuf) {
  const int b = blockIdx.x;
  const int h = threadIdx.x;
  const float aL = prm[4 * kH + h];
  float u = ut0[(size_t)b * kH + h];
  float vc[10];
#pragma unroll 1
  for (int cb = 0; cb < kC; cb += 10) {
#pragma unroll
    for (int j = 0; j < 10; ++j)
      vc[j] = vbuf[((size_t)b * kC + cb + j) * kH + h];  // independent loads, pipelined
#pragma unroll
    for (int j = 0; j < 10; ++j) {
      vbuf[((size_t)b * kC + cb + j) * kH + h] = u;
      u = aL * u + vc[j];
    }
  }
}

// ---------- K5: per-chunk softmax accumulation -> atomic into out ----------
// Row sums via in-register wave butterfly + tiny LDS (no 40KB tile).
__global__ __launch_bounds__(512) void chunk_soft_k(const unsigned short* __restrict__ Wxb,
                                                    const float* __restrict__ prm,
                                                    const float* __restrict__ ustart,
                                                    float* __restrict__ out) {
  __shared__ float part[kL][9];   // [row][wave] partials (pad 9)
  __shared__ float zinv[kL];
  const int bc = blockIdx.x;
  const int b = bc / kC, c = bc % kC;
  const int h = threadIdx.x;
  const int wv = h >> 6, lane = h & 63;
  const float sc = prm[h], sh = prm[kH + h];
  const float a = prm[2 * kH + h], oma = prm[3 * kH + h];
  float u = ustart[(size_t)bc * kH + h];
  const unsigned short* base = Wxb + ((size_t)b * kT + (size_t)c * kL) * kH + h;
  float e[kL];
#pragma unroll
  for (int i = 0; i < kL; ++i) {
    const float wvx = bf2f(base[(size_t)i * kH]) * sc + sh;
    u = a * u + oma * wvx;
    e[i] = __expf(u);  // |u| <~ 2 after BN+EWMA damping: no max-subtract needed
  }
#pragma unroll
  for (int i = 0; i < kL; ++i) {
    float s = e[i];
#pragma unroll
    for (int off = 32; off > 0; off >>= 1) s += __shfl_xor(s, off);
    if (lane == 0) part[i][wv] = s;
  }
  __syncthreads();
  if (h < kL) {
    float s = 0.f;
#pragma unroll
    for (int j = 0; j < 8; ++j) s += part[h][j];
    zinv[h] = 1.0f / s;
  }
  __syncthreads();
  float acc = 0.f;
#pragma unroll
  for (int i = 0; i < kL; ++i) acc += e[i] * zinv[i];
  atomicAdd(&out[(size_t)b * kH + h], acc);
}

}  // namespace

extern "C" void kernel_launch(void* const* d_in, const int* in_sizes, int n_in,
                              void* d_out, int out_size, void* d_ws, size_t ws_size,
                              hipStream_t stream) {
  const float* x = (const float*)d_in[0];      // [32,2000,512]
  const float* Wm = (const float*)d_in[1];     // [512,512]
  // d_in[2] = b: unused — BN mean subtraction cancels the bias exactly
  const float* alpha = (const float*)d_in[3];
  const float* gamma = (const float*)d_in[4];
  const float* beta = (const float*)d_in[5];
  const float* ut0 = (const float*)d_in[6];
  float* out = (float*)d_out;                  // [32,1,512]

  float* w = (float*)d_ws;
  float* vbuf = w;                             // 32*100*512 f
  float* sums = vbuf + (size_t)kB * kC * kH;   // 1024 f
  float* prm = sums + 2 * kH;                  // 2560 f
  __bf16* Wbf = (__bf16*)(prm + 5 * kH);       // 262,144 bf16
  unsigned short* Wxb = (unsigned short*)(Wbf + (size_t)kH * kD);  // 65.5 MB

  hipMemsetAsync(sums, 0, 2 * kH * sizeof(float), stream);
  hipMemsetAsync(out, 0, (size_t)kB * kH * sizeof(float), stream);
  wcvt_k<<<128, 256, 0, stream>>>(Wm, Wbf);
  gemm_k<<<kM / 64, 512, 0, stream>>>(x, Wbf, Wxb, sums);
  finalize_k<<<1, 512, 0, stream>>>(sums, alpha, gamma, beta, prm);
  chunk_agg_k<<<kB * kC, 256, 0, stream>>>(Wxb, prm, vbuf);
  chunk_scan_k<<<kB, 512, 0, stream>>>(ut0, prm, vbuf);
  chunk_soft_k<<<kB * kC, 512, 0, stream>>>(Wxb, prm, vbuf, out);
}

// Round 4
// 317.825 us; speedup vs baseline: 1.3673x; 1.3673x over previous
//
#include <hip/hip_runtime.h>
#include <hip/hip_bf16.h>
#include <stdint.h>

// ReadoutLayer: Wx = x @ W^T (+b cancels under BN), BatchNorm(train) over B*T,
// then ut = a*ut + (1-a)*wxn per t with acc += softmax(ut, axis=H).
// R4: atomic-free GEMM epilogue (R2/R3's 1M device-atomics on 4KB serialized the
// dispatch: WRITE_SIZE inflated 65->306MB with all pipes <7% busy). B staged via
// global_load_lds width=16 (m97 pattern), unpadded LDS, post-barrier A prefetch.
// Tail: raw-EWMA chunk agg (BN folded into boundary scan), no output atomics.

namespace {
constexpr int kB = 32;
constexpr int kT = 2000;
constexpr int kD = 512;
constexpr int kH = 512;
constexpr int kM = kB * kT;   // 64000 rows
constexpr int kL = 20;        // chunk length
constexpr int kC = kT / kL;   // 100 chunks per batch
constexpr float kALo = 0.81873075307798182f;  // exp(-1/5)
constexpr float kAHi = 0.96078943915232320f;  // exp(-1/25)

typedef __bf16 bf16x4 __attribute__((ext_vector_type(4)));
typedef __bf16 bf16x8 __attribute__((ext_vector_type(8)));
typedef float floatx16 __attribute__((ext_vector_type(16)));

__device__ __forceinline__ float bf2f(unsigned short u) {
  return __builtin_bit_cast(float, (unsigned)u << 16);
}
__device__ __forceinline__ float clipa(float a) {
  return fminf(fmaxf(a, kALo), kAHi);
}
__device__ __forceinline__ float pow20(float a) {
  const float a2 = a * a, a4 = a2 * a2, a5 = a4 * a;
  const float a10 = a5 * a5;
  return a10 * a10;
}
// async global->LDS, 16B per lane; LDS dest = wave-uniform base + lane*16
__device__ __forceinline__ void gld_lds16(const void* g, void* l) {
  __builtin_amdgcn_global_load_lds(
      (const __attribute__((address_space(1))) uint32_t*)g,
      (__attribute__((address_space(3))) uint32_t*)(uintptr_t)l, 16, 0, 0);
}

// ---------- K0: W f32 -> bf16 (once; L2/L3-resident for the GEMM) ----------
__global__ __launch_bounds__(256) void wcvt_k(const float* __restrict__ W,
                                              __bf16* __restrict__ Wbf) {
  const int t = blockIdx.x * 256 + threadIdx.x;
  const float4 a0 = ((const float4*)W)[t * 2];
  const float4 a1 = ((const float4*)W)[t * 2 + 1];
  bf16x8 v;
  v[0] = (__bf16)a0.x; v[1] = (__bf16)a0.y; v[2] = (__bf16)a0.z; v[3] = (__bf16)a0.w;
  v[4] = (__bf16)a1.x; v[5] = (__bf16)a1.y; v[6] = (__bf16)a1.z; v[7] = (__bf16)a1.w;
  *(bf16x8*)(Wbf + (size_t)t * 8) = v;
}

// ---------- K1: GEMM 64 rows x full 512 cols per block, atomic-free stats ----------
// 512 threads = 8 waves; wave w: row-tile rt=w>>2, col-tiles (w&3)*4..+4.
__global__ __launch_bounds__(512, 2) void gemm_k(const float* __restrict__ X,
                                                 const __bf16* __restrict__ Wbf,
                                                 unsigned short* __restrict__ Wxb,
                                                 float* __restrict__ partial) {
  __shared__ __bf16 As[64][32];    // unpadded: required by global_load_lds layout rules
  __shared__ __bf16 Bs[512][32];
  __shared__ float sred[2][kH];
  const int tid = threadIdx.x;
  const size_t row0 = (size_t)blockIdx.x * 64;
  const int w = tid >> 6, L = tid & 63;
  const int rt = w >> 2, ct0 = (w & 3) * 4;
  const int lhalf = L >> 5, l32 = L & 31;
  const int arow = tid >> 3, acol = (tid & 7) * 4;  // A staging: 1 float4/thread

  floatx16 acc[4] = {};
  const float* xbase = X + (row0 + arow) * kD + acol;
  float4 a_pre = *(const float4*)xbase;  // slab 0

#pragma unroll 1
  for (int s = 0; s < 16; ++s) {
    __syncthreads();  // prior MFMA ds_reads done before LDS overwrite
    bf16x4 av;
    av[0] = (__bf16)a_pre.x; av[1] = (__bf16)a_pre.y;
    av[2] = (__bf16)a_pre.z; av[3] = (__bf16)a_pre.w;
    *(bf16x4*)&As[arow][acol] = av;
    const int kk = s * 32;
#pragma unroll
    for (int j = 0; j < 4; ++j) {
      const int ci = j * 512 + w * 64 + L;  // 16B-chunk index into Bs
      const __bf16* src = Wbf + (size_t)(ci >> 2) * kD + kk + (ci & 3) * 8;
      gld_lds16(src, (char*)&Bs[0][0] + (size_t)ci * 16);
    }
    __syncthreads();  // vmcnt(0)+lgkmcnt(0): staging complete
    if (s < 15) a_pre = *(const float4*)(xbase + (s + 1) * 32);  // overlaps MFMA
#pragma unroll
    for (int kh = 0; kh < 2; ++kh) {
      const bf16x8 af = *(const bf16x8*)&As[rt * 32 + l32][kh * 16 + lhalf * 8];
#pragma unroll
      for (int c = 0; c < 4; ++c) {
        const bf16x8 bfr = *(const bf16x8*)&Bs[(ct0 + c) * 32 + l32][kh * 16 + lhalf * 8];
        acc[c] = __builtin_amdgcn_mfma_f32_32x32x16_bf16(af, bfr, acc[c], 0, 0, 0);
      }
    }
  }

  // ---- epilogue 1: column sums/sumsq -> LDS -> plain partial stores ----
  __syncthreads();
  sred[0][tid] = 0.f;
  sred[1][tid] = 0.f;
  __syncthreads();
#pragma unroll
  for (int c = 0; c < 4; ++c) {
    float s = 0.f, q = 0.f;
#pragma unroll
    for (int r = 0; r < 16; ++r) {
      const float v = acc[c][r];
      s += v;
      q += v * v;
    }
    s += __shfl_xor(s, 32);
    q += __shfl_xor(q, 32);
    if (lhalf == 0) {
      atomicAdd(&sred[0][(ct0 + c) * 32 + l32], s);  // LDS atomics only
      atomicAdd(&sred[1][(ct0 + c) * 32 + l32], q);
    }
  }
  // ---- epilogue 2: store Wx bf16, packed dword pairs via shfl ----
  // C/D layout (32x32): col = lane&31, row = 4*(lane>>5) + (reg&3) + 8*(reg>>2)
#pragma unroll
  for (int c = 0; c < 4; ++c) {
    const int col = (ct0 + c) * 32 + l32;
#pragma unroll
    for (int r = 0; r < 16; ++r) {
      const int row = rt * 32 + 4 * lhalf + (r & 3) + 8 * (r >> 2);
      const unsigned short u = __builtin_bit_cast(unsigned short, (__bf16)acc[c][r]);
      const unsigned un = __shfl_down((unsigned)u, 1);
      if ((l32 & 1) == 0)
        *(unsigned*)(Wxb + (row0 + row) * (size_t)kH + col) = (unsigned)u | (un << 16);
    }
  }
  __syncthreads();
  partial[(size_t)blockIdx.x * 1024 + tid] = sred[0][tid];
  partial[(size_t)blockIdx.x * 1024 + 512 + tid] = sred[1][tid];
}

// ---------- K2: reduce per-block partials (40 blocks x 25 rows) ----------
__global__ __launch_bounds__(512) void red1_k(const float* __restrict__ partial,
                                              float* __restrict__ sums) {
  const int tid = threadIdx.x;
  const int r0 = blockIdx.x * 25;
  float s0 = 0.f, s1 = 0.f;
#pragma unroll 5
  for (int r = 0; r < 25; ++r) {
    s0 += partial[(size_t)(r0 + r) * 1024 + tid];
    s1 += partial[(size_t)(r0 + r) * 1024 + 512 + tid];
  }
  atomicAdd(&sums[tid], s0);        // 40-deep contention: negligible
  atomicAdd(&sums[kH + tid], s1);
}

// ---------- K3: finalize BN scale/shift + alpha params ----------
// prm: [0]=scale [512]=shift [1024]=a [1536]=1-a [2048]=a^L
__global__ __launch_bounds__(512) void finalize_k(const float* __restrict__ sums,
                                                  const float* __restrict__ alpha,
                                                  const float* __restrict__ gamma,
                                                  const float* __restrict__ beta,
                                                  float* __restrict__ prm) {
  const int h = threadIdx.x;
  const float inv_n = 1.0f / (float)kM;
  const float mean = sums[h] * inv_n;
  const float var = sums[kH + h] * inv_n - mean * mean;
  const float sc = gamma[h] * rsqrtf(var + 1e-5f);
  const float sh = beta[h] - mean * sc;
  const float a = clipa(alpha[h]);
  prm[h] = sc;
  prm[kH + h] = sh;
  prm[2 * kH + h] = a;
  prm[3 * kH + h] = 1.0f - a;
  prm[4 * kH + h] = pow20(a);
}

// ---------- K4: per-chunk RAW EWMA (no BN dep -> runs right after gemm) ----------
__global__ __launch_bounds__(512) void agg_raw_k(const unsigned short* __restrict__ Wxb,
                                                 const float* __restrict__ alpha,
                                                 float* __restrict__ vbuf) {
  const int bc = blockIdx.x;
  const int b = bc / kC, c = bc % kC;
  const int h = threadIdx.x;
  const float a = clipa(alpha[h]);
  const float oma = 1.0f - a;
  const unsigned short* base = Wxb + ((size_t)b * kT + (size_t)c * kL) * kH + h;
  float v = 0.f;
#pragma unroll
  for (int i = 0; i < kL; ++i)
    v = a * v + oma * bf2f(base[(size_t)i * kH]);
  vbuf[(size_t)bc * kH + h] = v;
}

// ---------- K5: chunk-boundary scan, BN folded: u' = a^20 u + sc*v + sh*(1-a^20) ----------
__global__ __launch_bounds__(512) void scan_k(const float* __restrict__ ut0,
                                              const float* __restrict__ alpha,
                                              const float* __restrict__ prm,
                                              float* __restrict__ vbuf) {
  const int b = blockIdx.x;
  const int h = threadIdx.x;
  const float a20 = pow20(clipa(alpha[h]));
  const float sc = prm[h];
  const float shc = prm[kH + h] * (1.0f - a20);
  float u = ut0[(size_t)b * kH + h];
  float vc[10];
#pragma unroll 1
  for (int cb = 0; cb < kC; cb += 10) {
#pragma unroll
    for (int j = 0; j < 10; ++j)
      vc[j] = vbuf[((size_t)b * kC + cb + j) * kH + h];  // independent, pipelined
#pragma unroll
    for (int j = 0; j < 10; ++j) {
      vbuf[((size_t)b * kC + cb + j) * kH + h] = u;      // ustart for chunk
      u = a20 * u + sc * vc[j] + shc;
    }
  }
}

// ---------- K6: per-chunk softmax accumulation -> partial store ----------
__global__ __launch_bounds__(512) void soft_k(const unsigned short* __restrict__ Wxb,
                                              const float* __restrict__ prm,
                                              const float* __restrict__ ustart,
                                              float* __restrict__ accp) {
  __shared__ float part[kL][9];
  __shared__ float zinv[kL];
  const int bc = blockIdx.x;
  const int b = bc / kC, c = bc % kC;
  const int h = threadIdx.x;
  const int wv = h >> 6, lane = h & 63;
  const float sc = prm[h], sh = prm[kH + h];
  const float a = prm[2 * kH + h], oma = prm[3 * kH + h];
  float u = ustart[(size_t)bc * kH + h];
  const unsigned short* base = Wxb + ((size_t)b * kT + (size_t)c * kL) * kH + h;
  float e[kL];
#pragma unroll
  for (int i = 0; i < kL; ++i) {
    const float wvx = bf2f(base[(size_t)i * kH]) * sc + sh;
    u = a * u + oma * wvx;
    e[i] = __expf(u);  // |u| <~ 2 after BN+EWMA damping: no max-subtract needed
  }
#pragma unroll
  for (int i = 0; i < kL; ++i) {
    float s = e[i];
#pragma unroll
    for (int off = 32; off > 0; off >>= 1) s += __shfl_xor(s, off);
    if (lane == 0) part[i][wv] = s;
  }
  __syncthreads();
  if (h < kL) {
    float s = 0.f;
#pragma unroll
    for (int j = 0; j < 8; ++j) s += part[h][j];
    zinv[h] = 1.0f / s;
  }
  __syncthreads();
  float acc = 0.f;
#pragma unroll
  for (int i = 0; i < kL; ++i) acc += e[i] * zinv[i];
  accp[(size_t)bc * kH + h] = acc;
}

// ---------- K7: reduce chunk partials -> out ----------
__global__ __launch_bounds__(512) void out_red_k(const float* __restrict__ accp,
                                                 float* __restrict__ out) {
  const int b = blockIdx.x;
  const int h = threadIdx.x;
  float s = 0.f;
#pragma unroll 4
  for (int c = 0; c < kC; ++c) s += accp[((size_t)b * kC + c) * kH + h];
  out[(size_t)b * kH + h] = s;
}

}  // namespace

extern "C" void kernel_launch(void* const* d_in, const int* in_sizes, int n_in,
                              void* d_out, int out_size, void* d_ws, size_t ws_size,
                              hipStream_t stream) {
  const float* x = (const float*)d_in[0];      // [32,2000,512]
  const float* Wm = (const float*)d_in[1];     // [512,512]
  // d_in[2] = b: unused — BN mean subtraction cancels the bias exactly
  const float* alpha = (const float*)d_in[3];
  const float* gamma = (const float*)d_in[4];
  const float* beta = (const float*)d_in[5];
  const float* ut0 = (const float*)d_in[6];
  float* out = (float*)d_out;                  // [32,1,512]

  float* wsp = (float*)d_ws;
  float* vbuf = wsp;                                   // 3200*512 f
  float* accp = vbuf + (size_t)kB * kC * kH;           // 3200*512 f
  float* partial = accp + (size_t)kB * kC * kH;        // 1000*1024 f
  float* sums = partial + (size_t)1000 * 1024;         // 1024 f
  float* prm = sums + 2 * kH;                          // 2560 f
  __bf16* Wbf = (__bf16*)(prm + 5 * kH);               // 262144 bf16 (16B-aligned)
  unsigned short* Wxb = (unsigned short*)(Wbf + (size_t)kH * kD);  // 65.5 MB

  hipMemsetAsync(sums, 0, 2 * kH * sizeof(float), stream);
  wcvt_k<<<128, 256, 0, stream>>>(Wm, Wbf);
  gemm_k<<<kM / 64, 512, 0, stream>>>(x, Wbf, Wxb, partial);
  agg_raw_k<<<kB * kC, 512, 0, stream>>>(Wxb, alpha, vbuf);   // L3-hot Wxb
  red1_k<<<40, 512, 0, stream>>>(partial, sums);
  finalize_k<<<1, 512, 0, stream>>>(sums, alpha, gamma, beta, prm);
  scan_k<<<kB, 512, 0, stream>>>(ut0, alpha, prm, vbuf);
  soft_k<<<kB * kC, 512, 0, stream>>>(Wxb, prm, vbuf, accp);
  out_red_k<<<kB, 512, 0, stream>>>(accp, out);
}